// Round 2
// baseline (3566.997 us; speedup 1.0000x reference)
//
#include <hip/hip_runtime.h>
#include <hip/hip_bf16.h>

// V=32000 E=512 H=512 L=2 B=64 ML=64 T=32 -- float32 in/out, bf16 MFMA internally
typedef __bf16 bf16_t;
typedef bf16_t bf16x8 __attribute__((ext_vector_type(8)));
typedef bf16_t bf16x4 __attribute__((ext_vector_type(4)));
typedef float f32x4 __attribute__((ext_vector_type(4)));

#define MFMA(a, b, c) __builtin_amdgcn_mfma_f32_16x16x32_bf16((a), (b), (c), 0, 0, 0)

__device__ __forceinline__ float sigm(float x) { return 1.f / (1.f + __expf(-x)); }
__device__ __forceinline__ float tanh_f(float x) { return 1.f - 2.f / (__expf(2.f * x) + 1.f); }

__device__ __forceinline__ bf16x8 cvt8(const float* p) {
    f32x4 a = *(const f32x4*)p, b = *(const f32x4*)(p + 4);
    bf16x8 v;
#pragma unroll
    for (int i = 0; i < 4; ++i) { v[i] = (bf16_t)a[i]; v[4 + i] = (bf16_t)b[i]; }
    return v;
}

// ---------- software grid barrier (device-scope, monotonic counter) ----------
__device__ __forceinline__ void gbar(int* cnt, int target) {
    __syncthreads();  // drains vmcnt: all this block's stores are in L2 before t0 proceeds
    if (threadIdx.x == 0) {
        __threadfence();  // agent release: writeback L2 so other XCDs can see our stores
        __hip_atomic_fetch_add(cnt, 1, __ATOMIC_RELEASE, __HIP_MEMORY_SCOPE_AGENT);
        while (__hip_atomic_load(cnt, __ATOMIC_ACQUIRE, __HIP_MEMORY_SCOPE_AGENT) < target)
            __builtin_amdgcn_s_sleep(2);
        __threadfence();  // agent acquire: invalidate L1/L2 so we see other XCDs' stores
    }
    __syncthreads();
}

// ---------- f32 -> bf16 weight conversion (n % 8 == 0) ----------
__global__ void k_cvt(const float* __restrict__ src, bf16_t* __restrict__ dst, int n) {
    int i = (blockIdx.x * 256 + threadIdx.x) * 8;
    if (i < n) *(bf16x8*)(dst + i) = cvt8(src + i);
}

// ---------- init: c (fp32), h parity-0 (bf16), bias sums (fp32), barrier counter ----------
__global__ void k_init(const float* __restrict__ h0, const float* __restrict__ c0,
                       const float* __restrict__ bi, const float* __restrict__ bh,
                       float* __restrict__ c_f32, bf16_t* __restrict__ h_bf,
                       float* __restrict__ bsum, int* __restrict__ bar) {
    int idx = blockIdx.x * 256 + threadIdx.x;
    if (idx < 65536) { c_f32[idx] = c0[idx]; h_bf[idx] = (bf16_t)h0[idx]; }
    if (idx < 4096) bsum[idx] = bi[idx] + bh[idx];
    if (idx == 0) *bar = 0;
}

// ---------- precompute emb-dependent GEMMs: out[M,N] = Emb[tok](f32->bf16) @ Bm[:, koff:+512]^T ----------
__global__ __launch_bounds__(256) void k_pre(const float* __restrict__ emb,
                                             const int* __restrict__ cur, const int* __restrict__ gt,
                                             const bf16_t* __restrict__ Bm, int ldb, int koff,
                                             float* __restrict__ out, int ldo) {
    int tid = threadIdx.x, lane = tid & 63, w = tid >> 6;
    int m = lane & 15, q = lane >> 4;
    int mrow = blockIdx.x * 64 + w * 16 + m;
    int tok = (mrow < 64) ? cur[mrow] : gt[mrow - 64];
    const float* arow = emb + (size_t)tok * 512;
    int n0 = blockIdx.y * 64;
    const bf16_t* brow0 = Bm + (size_t)(n0 + m) * ldb + koff;
    f32x4 acc[4] = {};
    for (int ks = 0; ks < 16; ++ks) {
        int kc = ks * 32 + q * 8;
        bf16x8 a = cvt8(arow + kc);
#pragma unroll
        for (int nt = 0; nt < 4; ++nt) {
            bf16x8 b = *(const bf16x8*)(brow0 + (size_t)nt * 16 * ldb + kc);
            acc[nt] = MFMA(a, b, acc[nt]);
        }
    }
    int rbase = blockIdx.x * 64 + w * 16 + q * 4;
#pragma unroll
    for (int nt = 0; nt < 4; ++nt)
#pragma unroll
        for (int i = 0; i < 4; ++i)
            out[(size_t)(rbase + i) * ldo + n0 + nt * 16 + m] = acc[nt][i];
}

// ---------- LSTM cell (device fn; wg owns cols j0=wg*16 of all 4 gates) ----------
__device__ __forceinline__ void lstm_phase(int wg, int tid,
                                           const bf16_t* __restrict__ x,
                                           const bf16_t* __restrict__ hprev,
                                           const bf16_t* __restrict__ Wi,
                                           const bf16_t* __restrict__ Wh,
                                           const float* __restrict__ bsum,
                                           float* __restrict__ c,
                                           bf16_t* __restrict__ hout,
                                           bf16_t* __restrict__ xs_out) {
    int lane = tid & 63, w = tid >> 6;
    int m = lane & 15, q = lane >> 4;
    int j0 = wg * 16;
    const bf16_t* ax = x + (size_t)(w * 16 + m) * 512;
    const bf16_t* ah = hprev + (size_t)(w * 16 + m) * 512;
    f32x4 acc[4] = {};
    for (int ks = 0; ks < 16; ++ks) {
        int kc = ks * 32 + q * 8;
        bf16x8 a = *(const bf16x8*)(ax + kc);
#pragma unroll
        for (int g = 0; g < 4; ++g) {
            const bf16_t* bp = Wi + (size_t)(g * 512 + j0 + m) * 512 + kc;
            acc[g] = MFMA(a, *(const bf16x8*)bp, acc[g]);
        }
    }
    for (int ks = 0; ks < 16; ++ks) {
        int kc = ks * 32 + q * 8;
        bf16x8 a = *(const bf16x8*)(ah + kc);
#pragma unroll
        for (int g = 0; g < 4; ++g) {
            const bf16_t* bp = Wh + (size_t)(g * 512 + j0 + m) * 512 + kc;
            acc[g] = MFMA(a, *(const bf16x8*)bp, acc[g]);
        }
    }
    int j = j0 + m;
    float bs0 = bsum[j], bs1 = bsum[512 + j], bs2 = bsum[1024 + j], bs3 = bsum[1536 + j];
#pragma unroll
    for (int i = 0; i < 4; ++i) {
        int b = w * 16 + q * 4 + i;
        float ig = acc[0][i] + bs0;
        float fg = acc[1][i] + bs1;
        float gg = acc[2][i] + bs2;
        float og = acc[3][i] + bs3;
        size_t off = (size_t)b * 512 + j;
        float co = c[off];
        float cn = sigm(fg) * co + sigm(ig) * tanh_f(gg);
        float hn = sigm(og) * tanh_f(cn);
        c[off] = cn;
        hout[off] = (bf16_t)hn;
        if (xs_out) xs_out[off] = (bf16_t)hn;
    }
}

// ---------- fused T=32 recurrent loop: one kernel, 32 WGs x 256 thr, software grid barrier ----------
__global__ __launch_bounds__(256) void k_loop(const bf16_t* __restrict__ attn_W_bf,
                                              const bf16_t* __restrict__ attn_out_W_bf,
                                              const float* __restrict__ enc,
                                              const float* __restrict__ pre_s,
                                              const float* __restrict__ pre_r,
                                              const bf16_t* __restrict__ Wi_bf,
                                              const bf16_t* __restrict__ Wh_bf,
                                              const float* __restrict__ bsum,
                                              float* __restrict__ c_f32,
                                              bf16_t* __restrict__ h_bf,
                                              bf16_t* __restrict__ ctx_bf,
                                              bf16_t* __restrict__ rnn_bf,
                                              bf16_t* __restrict__ xs,
                                              int* __restrict__ bar) {
    __shared__ float s_p[2][64];
    int tid = threadIdx.x, lane = tid & 63, w = tid >> 6;
    int m = lane & 15, q = lane >> 4;
    int wg = blockIdx.x;
    int b0 = wg * 2;  // this WG owns batch rows b0, b0+1 in phase A
    int bt = 0;       // monotonic barrier target

    for (int t = 0; t < 32; ++t) {
        int p = t & 1;
        const bf16_t* h1p = h_bf + (size_t)p * 65536;
        const bf16_t* h2p = h1p + 32768;
        bf16_t* h1n = h_bf + (size_t)(p ^ 1) * 65536;
        bf16_t* h2n = h1n + 32768;

        // ---- phase A: scores (h2-part) + softmax + ctx for rows b0,b0+1 ----
        {
            // A rows: row r holds batch b0+(r&1); B: attn_W rows l=w*16..+16, k-offset 512 (h part)
            const bf16_t* aptr = h2p + (size_t)(b0 + (m & 1)) * 512;
            const bf16_t* bptr = attn_W_bf + (size_t)(w * 16 + m) * 1024 + 512;
            f32x4 acc = {};
            for (int ks = 0; ks < 16; ++ks) {
                int kc = ks * 32 + q * 8;
                acc = MFMA(*(const bf16x8*)(aptr + kc), *(const bf16x8*)(bptr + kc), acc);
            }
            if (q == 0) {
#pragma unroll
                for (int i = 0; i < 2; ++i)
                    s_p[i][w * 16 + m] =
                        acc[i] + pre_s[((size_t)t * 64 + b0 + i) * 64 + w * 16 + m];
            }
        }
        __syncthreads();
        // softmax over ML=64, wave r handles row r (full-wave butterfly)
        if (tid < 128) {
            int r = tid >> 6, l = tid & 63;
            float v = s_p[r][l];
            float mx = v;
#pragma unroll
            for (int off = 32; off; off >>= 1) mx = fmaxf(mx, __shfl_xor(mx, off));
            float e = __expf(v - mx);
            float s = e;
#pragma unroll
            for (int off = 32; off; off >>= 1) s += __shfl_xor(s, off);
            s_p[r][l] = e / s;
        }
        __syncthreads();
        // ctx[b,:] = sum_l p[b,l] * enc[l,b,:]  (2 rows x 128 threads x 4 floats)
        {
            int r = tid >> 7, c0 = (tid & 127) * 4;
            int b = b0 + r;
            f32x4 acc = {};
            const float* ebase = enc + (size_t)b * 512 + c0;
            for (int l = 0; l < 64; ++l) {
                float a = s_p[r][l];
                f32x4 e = *(const f32x4*)(ebase + (size_t)l * 32768);
#pragma unroll
                for (int i = 0; i < 4; ++i) acc[i] += a * e[i];
            }
            bf16x4 cv;
#pragma unroll
            for (int i = 0; i < 4; ++i) cv[i] = (bf16_t)acc[i];
            *(bf16x4*)(ctx_bf + (size_t)b * 512 + c0) = cv;
        }
        bt += 32; gbar(bar, bt);

        // ---- phase B: rnn_in = relu(pre_r + ctx @ Wo[:,512:]^T), N-split: cols wg*16..+16 ----
        {
            int j0 = wg * 16;
            const bf16_t* actx = ctx_bf + (size_t)(w * 16 + m) * 512;
            const bf16_t* bptr = attn_out_W_bf + (size_t)(j0 + m) * 1024 + 512;
            f32x4 acc = {};
            for (int ks = 0; ks < 16; ++ks) {
                int kc = ks * 32 + q * 8;
                acc = MFMA(*(const bf16x8*)(actx + kc), *(const bf16x8*)(bptr + kc), acc);
            }
            int jj = j0 + m;
#pragma unroll
            for (int i = 0; i < 4; ++i) {
                int b = w * 16 + q * 4 + i;
                float v = acc[i] + pre_r[((size_t)t * 64 + b) * 512 + jj];
                rnn_bf[(size_t)b * 512 + jj] = (bf16_t)fmaxf(v, 0.f);
            }
        }
        bt += 32; gbar(bar, bt);

        // ---- phase C: LSTM layer 1 ----
        lstm_phase(wg, tid, rnn_bf, h1p, Wi_bf, Wh_bf, bsum, c_f32, h1n, nullptr);
        bt += 32; gbar(bar, bt);

        // ---- phase D: LSTM layer 2 ----
        lstm_phase(wg, tid, h1n, h2p, Wi_bf + 1048576, Wh_bf + 1048576, bsum + 2048,
                   c_f32 + 32768, h2n, xs + (size_t)t * 32768);
        bt += 32; gbar(bar, bt);
    }
}

// ---------- generator GEMM: out[2048,32000](f32) = xs @ gen_W^T + gen_b ----------
__global__ __launch_bounds__(256) void k_gen(const bf16_t* __restrict__ xs,
                                             const bf16_t* __restrict__ gen_W,
                                             const float* __restrict__ gen_b,
                                             float* __restrict__ out) {
    __shared__ bf16_t sA[64 * 256];
    int tid = threadIdx.x, lane = tid & 63, w = tid >> 6;
    int m = lane & 15, q4 = lane >> 4;
    int m0 = blockIdx.x * 64, n0 = blockIdx.y * 256;
    f32x4 acc[4][4] = {};
    for (int ko = 0; ko < 2; ++ko) {
        __syncthreads();
#pragma unroll
        for (int it = 0; it < 8; ++it) {
            int idx = it * 256 + tid;
            int mr = idx >> 5, qc = idx & 31;
            bf16x8 v = *(const bf16x8*)(xs + (size_t)(m0 + mr) * 512 + ko * 256 + qc * 8);
            *(bf16x8*)(&sA[(mr * 32 + (qc ^ (mr & 7))) * 8]) = v;
        }
        __syncthreads();
        const bf16_t* bbase = gen_W + (size_t)(n0 + w * 64 + m) * 512 + ko * 256;
        for (int ks = 0; ks < 8; ++ks) {
            bf16x8 af[4];
#pragma unroll
            for (int mt = 0; mt < 4; ++mt) {
                int r = mt * 16 + m, chunk = ks * 4 + q4;
                af[mt] = *(const bf16x8*)(&sA[(r * 32 + (chunk ^ (r & 7))) * 8]);
            }
            int kc = ks * 32 + q4 * 8;
#pragma unroll
            for (int nt = 0; nt < 4; ++nt) {
                bf16x8 bfrag = *(const bf16x8*)(bbase + (size_t)nt * 16 * 512 + kc);
#pragma unroll
                for (int mt = 0; mt < 4; ++mt) acc[mt][nt] = MFMA(af[mt], bfrag, acc[mt][nt]);
            }
        }
    }
#pragma unroll
    for (int nt = 0; nt < 4; ++nt) {
        int col = n0 + w * 64 + nt * 16 + m;
        float bias = gen_b[col];
#pragma unroll
        for (int mt = 0; mt < 4; ++mt)
#pragma unroll
            for (int i = 0; i < 4; ++i) {
                int r = m0 + mt * 16 + q4 * 4 + i;
                out[(size_t)r * 32000 + col] = acc[mt][nt][i] + bias;
            }
    }
}

// ---------- tail: h_fin, c_fin (f32) ----------
__global__ void k_tail(const bf16_t* __restrict__ h_bf0, const float* __restrict__ c_f32,
                       float* __restrict__ out) {
    int idx = blockIdx.x * 256 + threadIdx.x;
    if (idx < 65536) {
        out[65536000 + idx] = (float)h_bf0[idx];
        out[65601536 + idx] = c_f32[idx];
    }
}

extern "C" void kernel_launch(void* const* d_in, const int* in_sizes, int n_in,
                              void* d_out, int out_size, void* d_ws, size_t ws_size,
                              hipStream_t stream) {
    const int* cur = (const int*)d_in[0];
    const float* h0 = (const float*)d_in[1];
    const float* c0 = (const float*)d_in[2];
    const float* enc = (const float*)d_in[3];
    const int* gt = (const int*)d_in[4];
    const float* emb = (const float*)d_in[6];
    const float* attn_W = (const float*)d_in[7];
    const float* attn_out_W = (const float*)d_in[8];
    const float* Wi = (const float*)d_in[9];
    const float* Wh = (const float*)d_in[10];
    const float* bi = (const float*)d_in[11];
    const float* bh = (const float*)d_in[12];
    const float* gen_W = (const float*)d_in[13];
    const float* gen_b = (const float*)d_in[14];
    float* out = (float*)d_out;

    char* ws = (char*)d_ws;
    float* c_f32 = (float*)(ws + 0);            // [2][64][512] f32
    bf16_t* h_bf = (bf16_t*)(ws + 262144);      // [2 parity][2 layer][64][512] bf16
    float* bsum = (float*)(ws + 524288);        // [2][2048] f32
    float* pre_s = (float*)(ws + 540672);       // [32][64][64] f32
    float* pre_r = (float*)(ws + 1064960);      // [32][64][512] f32
    bf16_t* rnn_bf = (bf16_t*)(ws + 5259264);   // [64][512] bf16
    bf16_t* xs = (bf16_t*)(ws + 5324800);       // [32][64][512] bf16
    bf16_t* attn_W_bf = (bf16_t*)(ws + 7421952);     // 65536
    bf16_t* attn_out_W_bf = (bf16_t*)(ws + 7553024); // 524288
    bf16_t* Wi_bf = (bf16_t*)(ws + 8601600);         // 2097152
    bf16_t* Wh_bf = (bf16_t*)(ws + 12795904);        // 2097152
    bf16_t* gen_W_bf = (bf16_t*)(ws + 16990208);     // 16384000
    bf16_t* ctx_bf = (bf16_t*)(ws + 49758208);       // [64][512] bf16
    int* bar = (int*)(ws + 49823744);                // barrier counter

    k_cvt<<<32, 256, 0, stream>>>(attn_W, attn_W_bf, 65536);
    k_cvt<<<256, 256, 0, stream>>>(attn_out_W, attn_out_W_bf, 524288);
    k_cvt<<<1024, 256, 0, stream>>>(Wi, Wi_bf, 2097152);
    k_cvt<<<1024, 256, 0, stream>>>(Wh, Wh_bf, 2097152);
    k_cvt<<<8000, 256, 0, stream>>>(gen_W, gen_W_bf, 16384000);
    k_init<<<256, 256, 0, stream>>>(h0, c0, bi, bh, c_f32, h_bf, bsum, bar);
    k_pre<<<dim3(32, 1), 256, 0, stream>>>(emb, cur, gt, attn_W_bf, 1024, 0, pre_s, 64);
    k_pre<<<dim3(32, 8), 256, 0, stream>>>(emb, cur, gt, attn_out_W_bf, 1024, 0, pre_r, 512);

    k_loop<<<32, 256, 0, stream>>>(attn_W_bf, attn_out_W_bf, enc, pre_s, pre_r,
                                   Wi_bf, Wh_bf, bsum, c_f32, h_bf, ctx_bf, rnn_bf, xs, bar);

    k_gen<<<dim3(32, 125), 256, 0, stream>>>(xs, gen_W_bf, gen_b, out);
    k_tail<<<256, 256, 0, stream>>>(h_bf, c_f32, out);
}

// Round 3
// 3477.536 us; speedup vs baseline: 1.0257x; 1.0257x over previous
//
#include <hip/hip_runtime.h>
#include <hip/hip_bf16.h>

// V=32000 E=512 H=512 L=2 B=64 ML=64 T=32 -- float32 in/out, bf16 MFMA internally
typedef __bf16 bf16_t;
typedef bf16_t bf16x8 __attribute__((ext_vector_type(8)));
typedef bf16_t bf16x4 __attribute__((ext_vector_type(4)));
typedef float f32x4 __attribute__((ext_vector_type(4)));

#define MFMA(a, b, c) __builtin_amdgcn_mfma_f32_16x16x32_bf16((a), (b), (c), 0, 0, 0)

__device__ __forceinline__ float sigm(float x) { return 1.f / (1.f + __expf(-x)); }
__device__ __forceinline__ float tanh_f(float x) { return 1.f - 2.f / (__expf(2.f * x) + 1.f); }

__device__ __forceinline__ bf16x8 cvt8(const float* p) {
    f32x4 a = *(const f32x4*)p, b = *(const f32x4*)(p + 4);
    bf16x8 v;
#pragma unroll
    for (int i = 0; i < 4; ++i) { v[i] = (bf16_t)a[i]; v[4 + i] = (bf16_t)b[i]; }
    return v;
}

// ---------- device-coherent (agent-scope, relaxed) access helpers ----------
// Relaxed agent atomics lower to sc0/sc1 accesses serviced at the device coherence
// point (IF$) with NO buffer_inv/buffer_wbl2 -- L2 weight residency is preserved.
__device__ __forceinline__ bf16x4 ld4c(const bf16_t* p) {
    unsigned long long u = __hip_atomic_load((const unsigned long long*)p,
                                             __ATOMIC_RELAXED, __HIP_MEMORY_SCOPE_AGENT);
    return __builtin_bit_cast(bf16x4, u);
}
__device__ __forceinline__ void st4c(bf16_t* p, bf16x4 v) {
    __hip_atomic_store((unsigned long long*)p, __builtin_bit_cast(unsigned long long, v),
                       __ATOMIC_RELAXED, __HIP_MEMORY_SCOPE_AGENT);
}
__device__ __forceinline__ bf16x8 ld8c(const bf16_t* p) {
    bf16x4 lo = ld4c(p), hi = ld4c(p + 4);
    bf16x8 r;
#pragma unroll
    for (int i = 0; i < 4; ++i) { r[i] = lo[i]; r[4 + i] = hi[i]; }
    return r;
}
__device__ __forceinline__ void st1c(bf16_t* p, bf16_t v) {
    __hip_atomic_store((unsigned short*)p, __builtin_bit_cast(unsigned short, v),
                       __ATOMIC_RELAXED, __HIP_MEMORY_SCOPE_AGENT);
}

// ---------- software grid barrier: NO agent fence (no L2 inv/wb) ----------
// __syncthreads() drains each thread's vmcnt, so all sc1 data stores are ack'd at
// the coherence point before thread 0 signals arrival.
__device__ __forceinline__ void gbar(int* cnt, int target) {
    __syncthreads();
    if (threadIdx.x == 0) {
        __hip_atomic_fetch_add(cnt, 1, __ATOMIC_RELAXED, __HIP_MEMORY_SCOPE_AGENT);
        while (__hip_atomic_load(cnt, __ATOMIC_RELAXED, __HIP_MEMORY_SCOPE_AGENT) < target)
            __builtin_amdgcn_s_sleep(2);
    }
    __syncthreads();
}

// ---------- f32 -> bf16 weight conversion (n % 8 == 0) ----------
__global__ void k_cvt(const float* __restrict__ src, bf16_t* __restrict__ dst, int n) {
    int i = (blockIdx.x * 256 + threadIdx.x) * 8;
    if (i < n) *(bf16x8*)(dst + i) = cvt8(src + i);
}

// ---------- init: c (fp32), h parity-0 (bf16), bias sums (fp32), barrier counter ----------
__global__ void k_init(const float* __restrict__ h0, const float* __restrict__ c0,
                       const float* __restrict__ bi, const float* __restrict__ bh,
                       float* __restrict__ c_f32, bf16_t* __restrict__ h_bf,
                       float* __restrict__ bsum, int* __restrict__ bar) {
    int idx = blockIdx.x * 256 + threadIdx.x;
    if (idx < 65536) { c_f32[idx] = c0[idx]; h_bf[idx] = (bf16_t)h0[idx]; }
    if (idx < 4096) bsum[idx] = bi[idx] + bh[idx];
    if (idx == 0) *bar = 0;
}

// ---------- precompute emb-dependent GEMMs: out[M,N] = Emb[tok](f32->bf16) @ Bm[:, koff:+512]^T ----------
__global__ __launch_bounds__(256) void k_pre(const float* __restrict__ emb,
                                             const int* __restrict__ cur, const int* __restrict__ gt,
                                             const bf16_t* __restrict__ Bm, int ldb, int koff,
                                             float* __restrict__ out, int ldo) {
    int tid = threadIdx.x, lane = tid & 63, w = tid >> 6;
    int m = lane & 15, q = lane >> 4;
    int mrow = blockIdx.x * 64 + w * 16 + m;
    int tok = (mrow < 64) ? cur[mrow] : gt[mrow - 64];
    const float* arow = emb + (size_t)tok * 512;
    int n0 = blockIdx.y * 64;
    const bf16_t* brow0 = Bm + (size_t)(n0 + m) * ldb + koff;
    f32x4 acc[4] = {};
    for (int ks = 0; ks < 16; ++ks) {
        int kc = ks * 32 + q * 8;
        bf16x8 a = cvt8(arow + kc);
#pragma unroll
        for (int nt = 0; nt < 4; ++nt) {
            bf16x8 b = *(const bf16x8*)(brow0 + (size_t)nt * 16 * ldb + kc);
            acc[nt] = MFMA(a, b, acc[nt]);
        }
    }
    int rbase = blockIdx.x * 64 + w * 16 + q * 4;
#pragma unroll
    for (int nt = 0; nt < 4; ++nt)
#pragma unroll
        for (int i = 0; i < 4; ++i)
            out[(size_t)(rbase + i) * ldo + n0 + nt * 16 + m] = acc[nt][i];
}

// ---------- LSTM cell (device fn; wg owns cols j0=wg*16 of all 4 gates) ----------
// x and hprev are cross-block buffers -> coherent loads; weights stay cached.
__device__ __forceinline__ void lstm_phase(int wg, int tid,
                                           const bf16_t* __restrict__ x,
                                           const bf16_t* __restrict__ hprev,
                                           const bf16_t* __restrict__ Wi,
                                           const bf16_t* __restrict__ Wh,
                                           const float* __restrict__ bsum,
                                           float* __restrict__ c,
                                           bf16_t* __restrict__ hout,
                                           bf16_t* __restrict__ xs_out) {
    int lane = tid & 63, w = tid >> 6;
    int m = lane & 15, q = lane >> 4;
    int j0 = wg * 16;
    const bf16_t* ax = x + (size_t)(w * 16 + m) * 512;
    const bf16_t* ah = hprev + (size_t)(w * 16 + m) * 512;
    f32x4 acc[4] = {};
    for (int ks = 0; ks < 16; ++ks) {
        int kc = ks * 32 + q * 8;
        bf16x8 a = ld8c(ax + kc);
#pragma unroll
        for (int g = 0; g < 4; ++g) {
            const bf16_t* bp = Wi + (size_t)(g * 512 + j0 + m) * 512 + kc;
            acc[g] = MFMA(a, *(const bf16x8*)bp, acc[g]);
        }
    }
    for (int ks = 0; ks < 16; ++ks) {
        int kc = ks * 32 + q * 8;
        bf16x8 a = ld8c(ah + kc);
#pragma unroll
        for (int g = 0; g < 4; ++g) {
            const bf16_t* bp = Wh + (size_t)(g * 512 + j0 + m) * 512 + kc;
            acc[g] = MFMA(a, *(const bf16x8*)bp, acc[g]);
        }
    }
    int j = j0 + m;
    float bs0 = bsum[j], bs1 = bsum[512 + j], bs2 = bsum[1024 + j], bs3 = bsum[1536 + j];
#pragma unroll
    for (int i = 0; i < 4; ++i) {
        int b = w * 16 + q * 4 + i;
        float ig = acc[0][i] + bs0;
        float fg = acc[1][i] + bs1;
        float gg = acc[2][i] + bs2;
        float og = acc[3][i] + bs3;
        size_t off = (size_t)b * 512 + j;
        float co = c[off];
        float cn = sigm(fg) * co + sigm(ig) * tanh_f(gg);
        float hn = sigm(og) * tanh_f(cn);
        c[off] = cn;                       // c is block-local (same block, same cols, all steps)
        st1c(hout + off, (bf16_t)hn);      // h crosses blocks -> coherent
        if (xs_out) xs_out[off] = (bf16_t)hn;  // consumed by k_gen after kernel end
    }
}

// ---------- fused T=32 recurrent loop: one kernel, 32 WGs x 256 thr, fence-free barriers ----------
__global__ __launch_bounds__(256) void k_loop(const bf16_t* __restrict__ attn_W_bf,
                                              const bf16_t* __restrict__ attn_out_W_bf,
                                              const float* __restrict__ enc,
                                              const float* __restrict__ pre_s,
                                              const float* __restrict__ pre_r,
                                              const bf16_t* __restrict__ Wi_bf,
                                              const bf16_t* __restrict__ Wh_bf,
                                              const float* __restrict__ bsum,
                                              float* __restrict__ c_f32,
                                              bf16_t* __restrict__ h_bf,
                                              bf16_t* __restrict__ ctx_bf,
                                              bf16_t* __restrict__ rnn_bf,
                                              bf16_t* __restrict__ xs,
                                              int* __restrict__ bar) {
    __shared__ float s_p[2][64];
    int tid = threadIdx.x, lane = tid & 63, w = tid >> 6;
    int m = lane & 15, q = lane >> 4;
    int wg = blockIdx.x;
    int b0 = wg * 2;  // this WG owns batch rows b0, b0+1 in phase A
    int bt = 0;       // monotonic barrier target

    for (int t = 0; t < 32; ++t) {
        int p = t & 1;
        const bf16_t* h1p = h_bf + (size_t)p * 65536;
        const bf16_t* h2p = h1p + 32768;
        bf16_t* h1n = h_bf + (size_t)(p ^ 1) * 65536;
        bf16_t* h2n = h1n + 32768;

        // ---- phase A: scores (h2-part) + softmax + ctx for rows b0,b0+1 ----
        {
            // A rows: row r holds batch b0+(r&1); B: attn_W rows l=w*16..+16, k-offset 512 (h part)
            const bf16_t* aptr = h2p + (size_t)(b0 + (m & 1)) * 512;
            const bf16_t* bptr = attn_W_bf + (size_t)(w * 16 + m) * 1024 + 512;
            f32x4 acc = {};
            for (int ks = 0; ks < 16; ++ks) {
                int kc = ks * 32 + q * 8;
                acc = MFMA(ld8c(aptr + kc), *(const bf16x8*)(bptr + kc), acc);
            }
            if (q == 0) {
#pragma unroll
                for (int i = 0; i < 2; ++i)
                    s_p[i][w * 16 + m] =
                        acc[i] + pre_s[((size_t)t * 64 + b0 + i) * 64 + w * 16 + m];
            }
        }
        __syncthreads();
        // softmax over ML=64, wave r handles row r (full-wave butterfly)
        if (tid < 128) {
            int r = tid >> 6, l = tid & 63;
            float v = s_p[r][l];
            float mx = v;
#pragma unroll
            for (int off = 32; off; off >>= 1) mx = fmaxf(mx, __shfl_xor(mx, off));
            float e = __expf(v - mx);
            float s = e;
#pragma unroll
            for (int off = 32; off; off >>= 1) s += __shfl_xor(s, off);
            s_p[r][l] = e / s;
        }
        __syncthreads();
        // ctx[b,:] = sum_l p[b,l] * enc[l,b,:]  (2 rows x 128 threads x 4 floats)
        {
            int r = tid >> 7, c0 = (tid & 127) * 4;
            int b = b0 + r;
            f32x4 acc = {};
            const float* ebase = enc + (size_t)b * 512 + c0;
            for (int l = 0; l < 64; ++l) {
                float a = s_p[r][l];
                f32x4 e = *(const f32x4*)(ebase + (size_t)l * 32768);
#pragma unroll
                for (int i = 0; i < 4; ++i) acc[i] += a * e[i];
            }
            bf16x4 cv;
#pragma unroll
            for (int i = 0; i < 4; ++i) cv[i] = (bf16_t)acc[i];
            st4c(ctx_bf + (size_t)b * 512 + c0, cv);
        }
        bt += 32; gbar(bar, bt);

        // ---- phase B: rnn_in = relu(pre_r + ctx @ Wo[:,512:]^T), N-split: cols wg*16..+16 ----
        {
            int j0 = wg * 16;
            const bf16_t* actx = ctx_bf + (size_t)(w * 16 + m) * 512;
            const bf16_t* bptr = attn_out_W_bf + (size_t)(j0 + m) * 1024 + 512;
            f32x4 acc = {};
            for (int ks = 0; ks < 16; ++ks) {
                int kc = ks * 32 + q * 8;
                acc = MFMA(ld8c(actx + kc), *(const bf16x8*)(bptr + kc), acc);
            }
            int jj = j0 + m;
#pragma unroll
            for (int i = 0; i < 4; ++i) {
                int b = w * 16 + q * 4 + i;
                float v = acc[i] + pre_r[((size_t)t * 64 + b) * 512 + jj];
                st1c(rnn_bf + (size_t)b * 512 + jj, (bf16_t)fmaxf(v, 0.f));
            }
        }
        bt += 32; gbar(bar, bt);

        // ---- phase C: LSTM layer 1 ----
        lstm_phase(wg, tid, rnn_bf, h1p, Wi_bf, Wh_bf, bsum, c_f32, h1n, nullptr);
        bt += 32; gbar(bar, bt);

        // ---- phase D: LSTM layer 2 ----
        lstm_phase(wg, tid, h1n, h2p, Wi_bf + 1048576, Wh_bf + 1048576, bsum + 2048,
                   c_f32 + 32768, h2n, xs + (size_t)t * 32768);
        bt += 32; gbar(bar, bt);
    }
}

// ---------- generator GEMM: out[2048,32000](f32) = xs @ gen_W^T + gen_b ----------
__global__ __launch_bounds__(256) void k_gen(const bf16_t* __restrict__ xs,
                                             const bf16_t* __restrict__ gen_W,
                                             const float* __restrict__ gen_b,
                                             float* __restrict__ out) {
    __shared__ bf16_t sA[64 * 256];
    int tid = threadIdx.x, lane = tid & 63, w = tid >> 6;
    int m = lane & 15, q4 = lane >> 4;
    int m0 = blockIdx.x * 64, n0 = blockIdx.y * 256;
    f32x4 acc[4][4] = {};
    for (int ko = 0; ko < 2; ++ko) {
        __syncthreads();
#pragma unroll
        for (int it = 0; it < 8; ++it) {
            int idx = it * 256 + tid;
            int mr = idx >> 5, qc = idx & 31;
            bf16x8 v = *(const bf16x8*)(xs + (size_t)(m0 + mr) * 512 + ko * 256 + qc * 8);
            *(bf16x8*)(&sA[(mr * 32 + (qc ^ (mr & 7))) * 8]) = v;
        }
        __syncthreads();
        const bf16_t* bbase = gen_W + (size_t)(n0 + w * 64 + m) * 512 + ko * 256;
        for (int ks = 0; ks < 8; ++ks) {
            bf16x8 af[4];
#pragma unroll
            for (int mt = 0; mt < 4; ++mt) {
                int r = mt * 16 + m, chunk = ks * 4 + q4;
                af[mt] = *(const bf16x8*)(&sA[(r * 32 + (chunk ^ (r & 7))) * 8]);
            }
            int kc = ks * 32 + q4 * 8;
#pragma unroll
            for (int nt = 0; nt < 4; ++nt) {
                bf16x8 bfrag = *(const bf16x8*)(bbase + (size_t)nt * 16 * 512 + kc);
#pragma unroll
                for (int mt = 0; mt < 4; ++mt) acc[mt][nt] = MFMA(af[mt], bfrag, acc[mt][nt]);
            }
        }
    }
#pragma unroll
    for (int nt = 0; nt < 4; ++nt) {
        int col = n0 + w * 64 + nt * 16 + m;
        float bias = gen_b[col];
#pragma unroll
        for (int mt = 0; mt < 4; ++mt)
#pragma unroll
            for (int i = 0; i < 4; ++i) {
                int r = m0 + mt * 16 + q4 * 4 + i;
                out[(size_t)r * 32000 + col] = acc[mt][nt][i] + bias;
            }
    }
}

// ---------- tail: h_fin, c_fin (f32) ----------
__global__ void k_tail(const bf16_t* __restrict__ h_bf0, const float* __restrict__ c_f32,
                       float* __restrict__ out) {
    int idx = blockIdx.x * 256 + threadIdx.x;
    if (idx < 65536) {
        out[65536000 + idx] = (float)h_bf0[idx];
        out[65601536 + idx] = c_f32[idx];
    }
}

extern "C" void kernel_launch(void* const* d_in, const int* in_sizes, int n_in,
                              void* d_out, int out_size, void* d_ws, size_t ws_size,
                              hipStream_t stream) {
    const int* cur = (const int*)d_in[0];
    const float* h0 = (const float*)d_in[1];
    const float* c0 = (const float*)d_in[2];
    const float* enc = (const float*)d_in[3];
    const int* gt = (const int*)d_in[4];
    const float* emb = (const float*)d_in[6];
    const float* attn_W = (const float*)d_in[7];
    const float* attn_out_W = (const float*)d_in[8];
    const float* Wi = (const float*)d_in[9];
    const float* Wh = (const float*)d_in[10];
    const float* bi = (const float*)d_in[11];
    const float* bh = (const float*)d_in[12];
    const float* gen_W = (const float*)d_in[13];
    const float* gen_b = (const float*)d_in[14];
    float* out = (float*)d_out;

    char* ws = (char*)d_ws;
    float* c_f32 = (float*)(ws + 0);            // [2][64][512] f32
    bf16_t* h_bf = (bf16_t*)(ws + 262144);      // [2 parity][2 layer][64][512] bf16
    float* bsum = (float*)(ws + 524288);        // [2][2048] f32
    float* pre_s = (float*)(ws + 540672);       // [32][64][64] f32
    float* pre_r = (float*)(ws + 1064960);      // [32][64][512] f32
    bf16_t* rnn_bf = (bf16_t*)(ws + 5259264);   // [64][512] bf16
    bf16_t* xs = (bf16_t*)(ws + 5324800);       // [32][64][512] bf16
    bf16_t* attn_W_bf = (bf16_t*)(ws + 7421952);     // 65536
    bf16_t* attn_out_W_bf = (bf16_t*)(ws + 7553024); // 524288
    bf16_t* Wi_bf = (bf16_t*)(ws + 8601600);         // 2097152
    bf16_t* Wh_bf = (bf16_t*)(ws + 12795904);        // 2097152
    bf16_t* gen_W_bf = (bf16_t*)(ws + 16990208);     // 16384000
    bf16_t* ctx_bf = (bf16_t*)(ws + 49758208);       // [64][512] bf16
    int* bar = (int*)(ws + 49823744);                // barrier counter

    k_cvt<<<32, 256, 0, stream>>>(attn_W, attn_W_bf, 65536);
    k_cvt<<<256, 256, 0, stream>>>(attn_out_W, attn_out_W_bf, 524288);
    k_cvt<<<1024, 256, 0, stream>>>(Wi, Wi_bf, 2097152);
    k_cvt<<<1024, 256, 0, stream>>>(Wh, Wh_bf, 2097152);
    k_cvt<<<8000, 256, 0, stream>>>(gen_W, gen_W_bf, 16384000);
    k_init<<<256, 256, 0, stream>>>(h0, c0, bi, bh, c_f32, h_bf, bsum, bar);
    k_pre<<<dim3(32, 1), 256, 0, stream>>>(emb, cur, gt, attn_W_bf, 1024, 0, pre_s, 64);
    k_pre<<<dim3(32, 8), 256, 0, stream>>>(emb, cur, gt, attn_out_W_bf, 1024, 0, pre_r, 512);

    k_loop<<<32, 256, 0, stream>>>(attn_W_bf, attn_out_W_bf, enc, pre_s, pre_r,
                                   Wi_bf, Wh_bf, bsum, c_f32, h_bf, ctx_bf, rnn_bf, xs, bar);

    k_gen<<<dim3(32, 125), 256, 0, stream>>>(xs, gen_W_bf, gen_b, out);
    k_tail<<<256, 256, 0, stream>>>(h_bf, c_f32, out);
}